// Round 10
// baseline (288.203 us; speedup 1.0000x reference)
//
#include <hip/hip_runtime.h>

#define HIDc 64
#define HEADSc 4
#define HCc 256   // HEADS*HID

typedef unsigned short ushort_t;
typedef unsigned int uint_t;
typedef __attribute__((ext_vector_type(8))) short bf16x8;
typedef __attribute__((ext_vector_type(4))) float f32x4;

__device__ inline ushort_t f2bf(float f) {  // RNE
    uint_t u = __float_as_uint(f);
    u += 0x7FFFu + ((u >> 16) & 1u);
    return (ushort_t)(u >> 16);
}
__device__ inline float bfu(uint_t lo16) { return __uint_as_float(lo16 << 16); }
__device__ inline float bflo(uint_t u) { return __uint_as_float(u << 16); }
__device__ inline float bfhi(uint_t u) { return __uint_as_float(u & 0xFFFF0000u); }
__device__ inline float lrelu(float a) { return a > 0.f ? a : 0.2f * a; }
__device__ inline float elu(float o)  { return o > 0.f ? o : (__expf(o) - 1.f); }

// ---------------- K0: weight prep: WgT bf16 [256][64], WlT bf16 [64][256] --
__global__ __launch_bounds__(256) void k0_prep(
    const float* __restrict__ Wg, const float* __restrict__ Wl,
    ushort_t* __restrict__ WgT, ushort_t* __restrict__ WlT)
{
    int i = blockIdx.x * 256 + threadIdx.x;
    if (i < 64 * 256) {                      // Wg [64][256] -> WgT [256][64]
        int k = i >> 8, n = i & 255;
        WgT[n * 64 + k] = f2bf(Wg[i]);
    } else {                                 // Wl [256][64] -> WlT [64][256]
        int j = i - 64 * 256;
        int k = j >> 6, n = j & 63;
        WlT[n * 256 + k] = f2bf(Wl[j]);
    }
}

// ---------------- K1: h = x @ W_gat via MFMA; fused a_src/a_dst ------------
// block = 4 waves; 32 nodes x 256 cols; wave w owns cols 64w..64w+63.
// MFMA accs staged to LDS -> coalesced h stores + in-LDS attention dots.
__global__ __launch_bounds__(256) void k1_mfma(
    const float* __restrict__ x, const ushort_t* __restrict__ WgT,
    const float* __restrict__ att_src, const float* __restrict__ att_dst,
    ushort_t* __restrict__ h, float* __restrict__ a_src, float* __restrict__ a_dst,
    int N)
{
    __shared__ ushort_t hs[32][264];         // pad: row stride 132 words (%32=4)

    const int t = threadIdx.x;
    const int w = t >> 6, l = t & 63;
    const int lr = l & 15, ko = l >> 4;
    const int base = blockIdx.x * 32;
    const int colb = w * 64;

    // A-frags: mt in {0,1} (16-row tiles), kb in {0,1} (K=32 halves)
    bf16x8 afr[2][2];
#pragma unroll
    for (int mt = 0; mt < 2; ++mt) {
        int row = base + mt * 16 + lr;
        int rowc = row < N ? row : N - 1;
        const float* xr = x + (size_t)rowc * HIDc + ko * 8;
#pragma unroll
        for (int kb = 0; kb < 2; ++kb) {
            float t0[8];
            *(float4*)t0       = *(const float4*)(xr + kb * 32);
            *(float4*)(t0 + 4) = *(const float4*)(xr + kb * 32 + 4);
            bf16x8 a;
#pragma unroll
            for (int j = 0; j < 8; ++j) a[j] = (short)f2bf(t0[j]);
            afr[mt][kb] = a;
        }
    }

    f32x4 acc[2][4];
#pragma unroll
    for (int mt = 0; mt < 2; ++mt)
#pragma unroll
        for (int nt = 0; nt < 4; ++nt) acc[mt][nt] = (f32x4)0.f;

#pragma unroll
    for (int nt = 0; nt < 4; ++nt) {
        const int col = colb + nt * 16 + lr;
        const ushort_t* wr = WgT + col * HIDc + ko * 8;
        bf16x8 b0 = *(const bf16x8*)wr;
        bf16x8 b1 = *(const bf16x8*)(wr + 32);
#pragma unroll
        for (int mt = 0; mt < 2; ++mt) {
            acc[mt][nt] = __builtin_amdgcn_mfma_f32_16x16x32_bf16(
                afr[mt][0], b0, acc[mt][nt], 0, 0, 0);
            acc[mt][nt] = __builtin_amdgcn_mfma_f32_16x16x32_bf16(
                afr[mt][1], b1, acc[mt][nt], 0, 0, 0);
        }
    }

    // stage C tile: row = mt*16 + ko*4 + r, col = colb + nt*16 + lr
#pragma unroll
    for (int mt = 0; mt < 2; ++mt)
#pragma unroll
        for (int r = 0; r < 4; ++r)
#pragma unroll
            for (int nt = 0; nt < 4; ++nt)
                hs[mt * 16 + ko * 4 + r][colb + nt * 16 + lr] =
                    f2bf(acc[mt][nt][r]);
    __syncthreads();

    // coalesced h store: wave w stores rows w, w+4, ... (64 lanes x uint2 = 512B/row)
    for (int rr = w; rr < 32; rr += 4) {
        int gn = base + rr;
        if (gn < N) {
            uint2 v = *(const uint2*)&hs[rr][l * 4];
            *(uint2*)&h[(size_t)gn * HCc + l * 4] = v;
        }
    }

    // a_src/a_dst: thread = (node, head, half); 32-ch dot + pair shuffle
    const int node = t >> 3, hd = (t >> 1) & 3, half = t & 1;
    const int gn2 = base + node;
    const int cb2 = hd * 64 + half * 32;
    float ps = 0.f, pd = 0.f;
#pragma unroll
    for (int j = 0; j < 32; ++j) {
        float hv = bfu((uint_t)hs[node][cb2 + j]);
        ps += hv * att_src[cb2 + j];
        pd += hv * att_dst[cb2 + j];
    }
    ps += __shfl_xor(ps, 1, 64);
    pd += __shfl_xor(pd, 1, 64);
    if (half == 0 && gn2 < N) {
        a_src[gn2 * HEADSc + hd] = ps;
        a_dst[gn2 * HEADSc + hd] = pd;
    }
}

// ---------------- K2a: count real in-degrees (int4 vectorized) -------------
__global__ void k2_count(const int* __restrict__ dst, int* __restrict__ counts,
                         int E)
{
    int i = (blockIdx.x * blockDim.x + threadIdx.x) * 4;
    if (i + 3 < E) {
        int4 d = *(const int4*)(dst + i);
        atomicAdd(&counts[d.x], 1);
        atomicAdd(&counts[d.y], 1);
        atomicAdd(&counts[d.z], 1);
        atomicAdd(&counts[d.w], 1);
    } else {
        for (int k = i; k < E; ++k) atomicAdd(&counts[dst[k]], 1);
    }
}

// ---------------- K2b: parallel scan (each element weighted count+1) -------
__global__ __launch_bounds__(256) void k2_scanA(
    const int* __restrict__ counts, int* __restrict__ bsum, int N)
{
    const int b = blockIdx.x, t = threadIdx.x;
    const int i0 = b * 1024 + t * 4;
    int s = 0;
    if (i0 + 3 < N) {
        int4 v = *(const int4*)(counts + i0);
        s = v.x + v.y + v.z + v.w + 4;
    } else {
        for (int k = 0; k < 4; ++k) if (i0 + k < N) s += counts[i0 + k] + 1;
    }
    const int lane = t & 63, wid = t >> 6;
#pragma unroll
    for (int o = 1; o < 64; o <<= 1) s += __shfl_xor(s, o, 64);
    __shared__ int ws[4];
    if (lane == 0) ws[wid] = s;
    __syncthreads();
    if (t == 0) bsum[b] = ws[0] + ws[1] + ws[2] + ws[3];
}

__global__ __launch_bounds__(64) void k2_scanB(
    const int* __restrict__ bsum, int* __restrict__ boff, int NB,
    int* __restrict__ offsets, int N)
{
    const int t = threadIdx.x;
    int carry = 0;
    for (int base = 0; base < NB; base += 64) {
        int v = (base + t < NB) ? bsum[base + t] : 0;
        int incl = v;
#pragma unroll
        for (int o = 1; o < 64; o <<= 1) {
            int u = __shfl_up(incl, o, 64);
            if (t >= o) incl += u;
        }
        if (base + t < NB) boff[base + t] = carry + incl - v;
        carry += __shfl(incl, 63, 64);
    }
    if (t == 0) offsets[N] = carry;                  // == E + N
}

__global__ __launch_bounds__(256) void k2_scanC(
    const int* __restrict__ counts, const int* __restrict__ boff,
    int* __restrict__ offsets, int* __restrict__ cursor, int N)
{
    const int b = blockIdx.x, t = threadIdx.x;
    const int i0 = b * 1024 + t * 4;
    int c0 = -1, c1 = -1, c2 = -1, c3 = -1;
    if (i0 + 3 < N) {
        int4 v = *(const int4*)(counts + i0);
        c0 = v.x; c1 = v.y; c2 = v.z; c3 = v.w;
    } else {
        if (i0     < N) c0 = counts[i0];
        if (i0 + 1 < N) c1 = counts[i0 + 1];
        if (i0 + 2 < N) c2 = counts[i0 + 2];
        if (i0 + 3 < N) c3 = counts[i0 + 3];
    }
    const int w0 = c0 >= 0 ? c0 + 1 : 0, w1 = c1 >= 0 ? c1 + 1 : 0;
    const int w2 = c2 >= 0 ? c2 + 1 : 0, w3 = c3 >= 0 ? c3 + 1 : 0;
    const int s4 = w0 + w1 + w2 + w3;
    const int lane = t & 63, wid = t >> 6;
    int incl = s4;
#pragma unroll
    for (int o = 1; o < 64; o <<= 1) {
        int u = __shfl_up(incl, o, 64);
        if (lane >= o) incl += u;
    }
    __shared__ int ws[4];
    if (lane == 63) ws[wid] = incl;
    __syncthreads();
    int woff = 0;
    for (int q = 0; q < wid; ++q) woff += ws[q];
    const int pref = boff[b] + woff + incl - s4;
    const int o0 = pref, o1 = o0 + w0, o2 = o1 + w1, o3 = o2 + w2;
    if (i0 + 3 < N) {
        *(int4*)(offsets + i0) = make_int4(o0, o1, o2, o3);
        *(int4*)(cursor  + i0) = make_int4(o0, o1, o2, o3);
    } else {
        if (c0 >= 0) { offsets[i0]     = o0; cursor[i0]     = o0; }
        if (c1 >= 0) { offsets[i0 + 1] = o1; cursor[i0 + 1] = o1; }
        if (c2 >= 0) { offsets[i0 + 2] = o2; cursor[i0 + 2] = o2; }
        if (c3 >= 0) { offsets[i0 + 3] = o3; cursor[i0 + 3] = o3; }
    }
}

// ---------------- K2c: fill CSR (edges int4; self-loops to last slot) ------
__global__ void k2_fill(const int* __restrict__ ei, const int* __restrict__ offsets,
                        int* __restrict__ cursor, int* __restrict__ csr_src,
                        int E, int N, int EB4)
{
    int gid = blockIdx.x * blockDim.x + threadIdx.x;
    if (gid < EB4) {
        int i = gid * 4;
        if (i + 3 < E) {
            int4 s4 = *(const int4*)(ei + i);
            int4 d4 = *(const int4*)(ei + E + i);
            int p;
            p = atomicAdd(&cursor[d4.x], 1); csr_src[p] = s4.x;
            p = atomicAdd(&cursor[d4.y], 1); csr_src[p] = s4.y;
            p = atomicAdd(&cursor[d4.z], 1); csr_src[p] = s4.z;
            p = atomicAdd(&cursor[d4.w], 1); csr_src[p] = s4.w;
        } else {
            for (int k = i; k < E; ++k) {
                int p = atomicAdd(&cursor[ei[E + k]], 1);
                csr_src[p] = ei[k];
            }
        }
    } else {
        int n = gid - EB4;                   // self-loop: last slot of segment
        if (n < N) csr_src[offsets[n + 1] - 1] = n;
    }
}

// ---------------- K3: one wave per node, 2 edges/iteration -----------------
// lanes 0-31: even edges, lanes 32-63: odd edges; lane covers 8 channels
// (uint4 = 16B of the 512B row). Barrier-free (wave-private LDS slabs).
__global__ __launch_bounds__(256) void k3_aggregate(
    const uint4* __restrict__ h4,
    const float4* __restrict__ a_src4,
    const float4* __restrict__ a_dst4,
    const int* __restrict__ offsets, const int* __restrict__ csr_src,
    const float4* __restrict__ bias4,
    uint4* __restrict__ act4, int N)
{
    __shared__ float s_p[HEADSc][64 * 4];
    __shared__ int   s_src[HEADSc][64];

    const int wid = threadIdx.x >> 6, lane = threadIdx.x & 63;
    const int n = blockIdx.x * 4 + wid;
    if (n >= N) return;

    const int beg = offsets[n], end = offsets[n + 1];
    const float4 adst = a_dst4[n];
    const int eh = lane >> 5, li = lane & 31;
    const int head = li >> 3;                // channel group li*8.. -> head

    float acc[8] = {0.f, 0.f, 0.f, 0.f, 0.f, 0.f, 0.f, 0.f};
    float den = 0.f;

    float* pw = s_p[wid];
    int*   sw = s_src[wid];

    for (int cb = beg; cb < end; cb += 64) {
        const int cnt = min(64, end - cb);
        // ---- phase 1: lane == edge slot; p for all 4 heads ----
        const bool valid = lane < cnt;
        const int sn = valid ? csr_src[cb + lane] : 0;
        const float4 as = a_src4[sn];
        float p0 = valid ? __expf(lrelu(as.x + adst.x)) : 0.f;
        float p1 = valid ? __expf(lrelu(as.y + adst.y)) : 0.f;
        float p2 = valid ? __expf(lrelu(as.z + adst.z)) : 0.f;
        float p3 = valid ? __expf(lrelu(as.w + adst.w)) : 0.f;
        ((float4*)pw)[lane] = make_float4(p0, p1, p2, p3);
        sw[lane] = sn;
        // same-wave LDS RAW: compiler inserts lgkmcnt, no barrier needed

        // ---- phase 2: pair loop; e may over-run to a zeroed slot ----
#pragma unroll 2
        for (int e2 = 0; e2 < cnt; e2 += 2) {
            const int   e  = e2 + eh;
            const int   sv = sw[e];
            const float pe = pw[e * 4 + head];
            den += pe;
            const uint4 v = h4[(uint_t)sv * 32u + li];
            acc[0] += pe * bflo(v.x); acc[1] += pe * bfhi(v.x);
            acc[2] += pe * bflo(v.y); acc[3] += pe * bfhi(v.y);
            acc[4] += pe * bflo(v.z); acc[5] += pe * bfhi(v.z);
            acc[6] += pe * bflo(v.w); acc[7] += pe * bfhi(v.w);
        }
    }

    // combine the two half-wave partials
#pragma unroll
    for (int q = 0; q < 8; ++q) acc[q] += __shfl_xor(acc[q], 32, 64);
    den += __shfl_xor(den, 32, 64);

    if (eh == 0) {
        const float r = 1.f / (den + 1e-16f);
        const float4 b0 = bias4[li * 2], b1 = bias4[li * 2 + 1];
        const float o0 = elu(acc[0] * r + b0.x);
        const float o1 = elu(acc[1] * r + b0.y);
        const float o2 = elu(acc[2] * r + b0.z);
        const float o3 = elu(acc[3] * r + b0.w);
        const float o4 = elu(acc[4] * r + b1.x);
        const float o5 = elu(acc[5] * r + b1.y);
        const float o6 = elu(acc[6] * r + b1.z);
        const float o7 = elu(acc[7] * r + b1.w);
        uint4 ov;
        ov.x = (uint_t)f2bf(o0) | ((uint_t)f2bf(o1) << 16);
        ov.y = (uint_t)f2bf(o2) | ((uint_t)f2bf(o3) << 16);
        ov.z = (uint_t)f2bf(o4) | ((uint_t)f2bf(o5) << 16);
        ov.w = (uint_t)f2bf(o6) | ((uint_t)f2bf(o7) << 16);
        act4[(uint_t)n * 32u + li] = ov;
    }
}

// ---------------- K4: out = act @ W_lin + b_lin via MFMA -------------------
// block = 4 waves = 64 nodes; wave w owns rows base+16w..+15, all 64 cols.
__global__ __launch_bounds__(256) void k4_mfma(
    const ushort_t* __restrict__ act, const ushort_t* __restrict__ WlT,
    const float* __restrict__ bl, float* __restrict__ out, int N)
{
    const int w = threadIdx.x >> 6, l = threadIdx.x & 63;
    const int lr = l & 15, ko = l >> 4;
    const int base = blockIdx.x * 64 + w * 16;

    f32x4 acc[4];
#pragma unroll
    for (int nt = 0; nt < 4; ++nt) acc[nt] = (f32x4)0.f;

    int row = base + lr;
    int rowc = row < N ? row : N - 1;
    const ushort_t* ar = act + (size_t)rowc * HCc + ko * 8;

#pragma unroll
    for (int kb = 0; kb < 8; ++kb) {
        bf16x8 a = *(const bf16x8*)(ar + kb * 32);
#pragma unroll
        for (int nt = 0; nt < 4; ++nt) {
            const int col = nt * 16 + lr;
            bf16x8 b = *(const bf16x8*)(WlT + col * HCc + kb * 32 + ko * 8);
            acc[nt] = __builtin_amdgcn_mfma_f32_16x16x32_bf16(a, b, acc[nt], 0, 0, 0);
        }
    }

#pragma unroll
    for (int r = 0; r < 4; ++r) {
        int orow = base + ko * 4 + r;
        if (orow < N) {
#pragma unroll
            for (int nt = 0; nt < 4; ++nt)
                out[(size_t)orow * HIDc + nt * 16 + lr] = acc[nt][r] + bl[nt * 16 + lr];
        }
    }
}

// ---------------------------------------------------------------------------
extern "C" void kernel_launch(void* const* d_in, const int* in_sizes, int n_in,
                              void* d_out, int out_size, void* d_ws, size_t ws_size,
                              hipStream_t stream)
{
    const float* x       = (const float*)d_in[0];
    const int*   ei      = (const int*)  d_in[1];
    const float* Wg      = (const float*)d_in[2];
    const float* att_src = (const float*)d_in[3];
    const float* att_dst = (const float*)d_in[4];
    const float* bias_g  = (const float*)d_in[5];
    const float* Wl      = (const float*)d_in[6];
    const float* bl      = (const float*)d_in[7];
    float* out = (float*)d_out;

    const int N = in_sizes[0] / HIDc;       // 50000
    const int E = in_sizes[1] / 2;          // 800000
    const int NB = (N + 1023) / 1024;
    const int EB4 = (E + 3) / 4;

    char* w = (char*)d_ws;
    size_t off = 0;
    auto carve = [&](size_t bytes) {
        void* p = w + off;
        off = (off + bytes + 255) & ~(size_t)255;
        return p;
    };
    ushort_t* h     = (ushort_t*)carve((size_t)N * HCc * 2);
    ushort_t* act   = (ushort_t*)carve((size_t)N * HCc * 2);
    float* a_src    = (float*)carve((size_t)N * HEADSc * 4);
    float* a_dst    = (float*)carve((size_t)N * HEADSc * 4);
    int*   counts   = (int*)  carve((size_t)N * 4);
    int*   offsets  = (int*)  carve((size_t)(N + 1) * 4);
    int*   cursor   = (int*)  carve((size_t)N * 4);
    int*   csr_src  = (int*)  carve((size_t)(E + N) * 4);
    int*   bsum     = (int*)  carve((size_t)NB * 4);
    int*   boff     = (int*)  carve((size_t)NB * 4);
    ushort_t* WgT   = (ushort_t*)carve((size_t)HIDc * HCc * 2);
    ushort_t* WlT   = (ushort_t*)carve((size_t)HCc * HIDc * 2);
    (void)ws_size; (void)n_in; (void)out_size;

    hipMemsetAsync(counts, 0, (size_t)N * 4, stream);

    k0_prep<<<128, 256, 0, stream>>>(Wg, Wl, WgT, WlT);
    k1_mfma<<<(N + 31) / 32, 256, 0, stream>>>(x, WgT, att_src, att_dst,
                                               h, a_src, a_dst, N);
    k2_count<<<(EB4 + 255) / 256, 256, 0, stream>>>(ei + E, counts, E);
    k2_scanA<<<NB, 256, 0, stream>>>(counts, bsum, N);
    k2_scanB<<<1, 64, 0, stream>>>(bsum, boff, NB, offsets, N);
    k2_scanC<<<NB, 256, 0, stream>>>(counts, boff, offsets, cursor, N);
    k2_fill<<<(EB4 + N + 255) / 256, 256, 0, stream>>>(ei, offsets, cursor,
                                                       csr_src, E, N, EB4);
    k3_aggregate<<<(N + 3) / 4, 256, 0, stream>>>(
        (const uint4*)h, (const float4*)a_src, (const float4*)a_dst,
        offsets, csr_src, (const float4*)bias_g, (uint4*)act, N);
    k4_mfma<<<(N + 63) / 64, 256, 0, stream>>>(act, WlT, bl, out, N);
}